// Round 5
// baseline (455.131 us; speedup 1.0000x reference)
//
#include <hip/hip_runtime.h>

// Problem dims
#define Bn   256
#define Tn   1024
#define INn  128
#define Hn   10
#define OUTn 128
#define BTn  (Bn * Tn)   // 262144 rows

// =====================================================================
// K1 v2: LDS reads widened b32 -> b128 (neutral last round, kept).
// =====================================================================
__global__ __launch_bounds__(256) void k1_inproj(
    const float* __restrict__ x,
    const float* __restrict__ Wih0,
    const float* __restrict__ bih0,
    const float* __restrict__ bhh0,
    float* __restrict__ xp0)
{
    __shared__ float Ws[Hn][INn];   // 5 KB, rows 512B -> float4-aligned
    __shared__ float bs[16];
    const int tid = threadIdx.x;
    for (int idx = tid; idx < Hn * INn / 4; idx += 256)   // coalesced staging
        reinterpret_cast<float4*>(&Ws[0][0])[idx] =
            reinterpret_cast<const float4*>(Wih0)[idx];
    if (tid < 16) bs[tid] = (tid < Hn) ? (bih0[tid] + bhh0[tid]) : 0.f;
    __syncthreads();

    const int row = blockIdx.x * 256 + tid;                 // grid = BTn/256
    const float4* xr = reinterpret_cast<const float4*>(x + (size_t)row * INn);

    float acc[Hn];
    #pragma unroll
    for (int j = 0; j < Hn; ++j) acc[j] = bs[j];

    #pragma unroll
    for (int c = 0; c < INn / 4; ++c) {
        float4 v = xr[c];
        #pragma unroll
        for (int j = 0; j < Hn; ++j) {
            const float4 w = *reinterpret_cast<const float4*>(&Ws[j][c * 4]);
            acc[j] = fmaf(v.x, w.x, acc[j]);
            acc[j] = fmaf(v.y, w.y, acc[j]);
            acc[j] = fmaf(v.z, w.z, acc[j]);
            acc[j] = fmaf(v.w, w.w, acc[j]);
        }
    }
    float4* op = reinterpret_cast<float4*>(xp0 + (size_t)row * 16);
    op[0] = make_float4(acc[0], acc[1], acc[2], acc[3]);
    op[1] = make_float4(acc[4], acc[5], acc[6], acc[7]);
    op[2] = make_float4(acc[8], acc[9], 0.f, 0.f);
    op[3] = make_float4(0.f, 0.f, 0.f, 0.f);
}

// =====================================================================
// K2 v7: DPP-rotation recurrence. One chain per 16-lane DPP row
// (4 chains/wave, grid=Bn/4), all state exchange via row_ror on the
// VALU pipe with VGPR destinations.
//  Evidence: v5 readlane=295cy/step (SGPR-slot serialization),
//  v6 ds_swizzle=352cy/step (LDS pipe ~16cy/op at 1 wave). DPP is the
//  only broadcast that stays VALU+VGPR. Weights are pre-permuted per
//  lane so  sum_k W[j,k] h[k] = sum_r W'[j][r] * ror_r(h); the mov_dpp
//  is single-use so GCNDPPCombine can fold it into v_fmac_f32_dpp.
//  Rotation direction resolved at runtime by a DPP probe (delta).
//  Both layers now in the SAME row -> layer2 uses same-step h1
//  (rotations of the just-computed value); no pipeline lag, no
//  epilogue, junk lanes (j>=10) have all-zero weights/bias/x so they
//  stay exactly 0.
// =====================================================================
static __device__ __forceinline__ void pinv(float& v) {
    asm volatile("" : "+v"(v));
}
// row_ror:R within each 16-lane row; VALU op, VGPR dest. R must be a literal 1..15.
#define ROTR(v, R) __int_as_float(__builtin_amdgcn_mov_dpp(__float_as_int(v), 0x120 + (R), 0xf, 0xf, false))

#define STEP(XV, YV) do {                                               \
    float d0 = biasv, d1 = 0.f, d2 = 0.f, d3 = 0.f;                     \
    d0 = fmaf(vh2,          Wb0,  d0);                                  \
    d1 = fmaf(ROTR(vh2, 1), Wb1,  d1);                                  \
    d2 = fmaf(ROTR(vh2, 2), Wb2,  d2);                                  \
    d3 = fmaf(ROTR(vh2, 3), Wb3,  d3);                                  \
    d0 = fmaf(ROTR(vh2, 4), Wb4,  d0);                                  \
    d1 = fmaf(ROTR(vh2, 5), Wb5,  d1);                                  \
    d2 = fmaf(ROTR(vh2, 6), Wb6,  d2);                                  \
    d3 = fmaf(ROTR(vh2, 7), Wb7,  d3);                                  \
    d0 = fmaf(ROTR(vh2, 8), Wb8,  d0);                                  \
    d1 = fmaf(ROTR(vh2, 9), Wb9,  d1);                                  \
    d2 = fmaf(ROTR(vh2,10), Wb10, d2);                                  \
    d3 = fmaf(ROTR(vh2,11), Wb11, d3);                                  \
    d0 = fmaf(ROTR(vh2,12), Wb12, d0);                                  \
    d1 = fmaf(ROTR(vh2,13), Wb13, d1);                                  \
    d2 = fmaf(ROTR(vh2,14), Wb14, d2);                                  \
    d3 = fmaf(ROTR(vh2,15), Wb15, d3);                                  \
    float c0 = (XV), c1 = 0.f, c2 = 0.f, c3 = 0.f;                      \
    c0 = fmaf(vh1,          Wa0,  c0);                                  \
    c1 = fmaf(ROTR(vh1, 1), Wa1,  c1);                                  \
    c2 = fmaf(ROTR(vh1, 2), Wa2,  c2);                                  \
    c3 = fmaf(ROTR(vh1, 3), Wa3,  c3);                                  \
    c0 = fmaf(ROTR(vh1, 4), Wa4,  c0);                                  \
    c1 = fmaf(ROTR(vh1, 5), Wa5,  c1);                                  \
    c2 = fmaf(ROTR(vh1, 6), Wa6,  c2);                                  \
    c3 = fmaf(ROTR(vh1, 7), Wa7,  c3);                                  \
    c0 = fmaf(ROTR(vh1, 8), Wa8,  c0);                                  \
    c1 = fmaf(ROTR(vh1, 9), Wa9,  c1);                                  \
    c2 = fmaf(ROTR(vh1,10), Wa10, c2);                                  \
    c3 = fmaf(ROTR(vh1,11), Wa11, c3);                                  \
    c0 = fmaf(ROTR(vh1,12), Wa12, c0);                                  \
    c1 = fmaf(ROTR(vh1,13), Wa13, c1);                                  \
    c2 = fmaf(ROTR(vh1,14), Wa14, c2);                                  \
    c3 = fmaf(ROTR(vh1,15), Wa15, c3);                                  \
    const float h1n = fmaxf((c0 + c1) + (c2 + c3), 0.f);                \
    d0 = fmaf(h1n,          Wc0,  d0);                                  \
    d1 = fmaf(ROTR(h1n, 1), Wc1,  d1);                                  \
    d2 = fmaf(ROTR(h1n, 2), Wc2,  d2);                                  \
    d3 = fmaf(ROTR(h1n, 3), Wc3,  d3);                                  \
    d0 = fmaf(ROTR(h1n, 4), Wc4,  d0);                                  \
    d1 = fmaf(ROTR(h1n, 5), Wc5,  d1);                                  \
    d2 = fmaf(ROTR(h1n, 6), Wc6,  d2);                                  \
    d3 = fmaf(ROTR(h1n, 7), Wc7,  d3);                                  \
    d0 = fmaf(ROTR(h1n, 8), Wc8,  d0);                                  \
    d1 = fmaf(ROTR(h1n, 9), Wc9,  d1);                                  \
    d2 = fmaf(ROTR(h1n,10), Wc10, d2);                                  \
    d3 = fmaf(ROTR(h1n,11), Wc11, d3);                                  \
    d0 = fmaf(ROTR(h1n,12), Wc12, d0);                                  \
    d1 = fmaf(ROTR(h1n,13), Wc13, d1);                                  \
    d2 = fmaf(ROTR(h1n,14), Wc14, d2);                                  \
    d3 = fmaf(ROTR(h1n,15), Wc15, d3);                                  \
    const float h2n = fmaxf((d0 + d1) + (d2 + d3), 0.f);                \
    vh1 = h1n; vh2 = h2n; (YV) = h2n;                                   \
} while (0)

__global__ __launch_bounds__(64, 1) void k2_recur(
    const float* __restrict__ xp0,
    const float* __restrict__ Whh0,
    const float* __restrict__ Wih1,
    const float* __restrict__ Whh1,
    const float* __restrict__ bih1,
    const float* __restrict__ bhh1,
    float* __restrict__ h2seq,
    float* __restrict__ hidden)   // [2, Bn, Hn] f32 (tail of d_out)
{
    const int lane = threadIdx.x;          // all 64 lanes active (4 rows)
    const int jl   = lane & 15;            // position within DPP row
    const int row  = lane >> 4;            // chain within wave
    const int b    = blockIdx.x * 4 + row; // grid = Bn/4 = 64

    // runtime direction probe: sigma_1(j) under row_ror:1
    const int delta = (__builtin_amdgcn_mov_dpp(jl, 0x121, 0xf, 0xf, false) - jl) & 15;

    const bool okj  = (jl < Hn);
    const int  jrow = (okj ? jl : 0) * Hn;

    float Wa0,Wa1,Wa2,Wa3,Wa4,Wa5,Wa6,Wa7,Wa8,Wa9,Wa10,Wa11,Wa12,Wa13,Wa14,Wa15;
    float Wb0,Wb1,Wb2,Wb3,Wb4,Wb5,Wb6,Wb7,Wb8,Wb9,Wb10,Wb11,Wb12,Wb13,Wb14,Wb15;
    float Wc0,Wc1,Wc2,Wc3,Wc4,Wc5,Wc6,Wc7,Wc8,Wc9,Wc10,Wc11,Wc12,Wc13,Wc14,Wc15;

    #define LDW(R) do {                                                 \
        const int  kk = (jl + (R) * delta) & 15;                        \
        const bool v  = okj && (kk < Hn);                               \
        const int  ii = jrow + (v ? kk : 0);                            \
        Wa##R = v ? Whh0[ii] : 0.f;                                     \
        Wb##R = v ? Whh1[ii] : 0.f;                                     \
        Wc##R = v ? Wih1[ii] : 0.f;                                     \
    } while (0)
    LDW(0);  LDW(1);  LDW(2);  LDW(3);  LDW(4);  LDW(5);  LDW(6);  LDW(7);
    LDW(8);  LDW(9);  LDW(10); LDW(11); LDW(12); LDW(13); LDW(14); LDW(15);
    #undef LDW

    float biasv = okj ? (bih1[jl] + bhh1[jl]) : 0.f;

    pinv(Wa0); pinv(Wa1); pinv(Wa2); pinv(Wa3); pinv(Wa4); pinv(Wa5); pinv(Wa6); pinv(Wa7);
    pinv(Wa8); pinv(Wa9); pinv(Wa10); pinv(Wa11); pinv(Wa12); pinv(Wa13); pinv(Wa14); pinv(Wa15);
    pinv(Wb0); pinv(Wb1); pinv(Wb2); pinv(Wb3); pinv(Wb4); pinv(Wb5); pinv(Wb6); pinv(Wb7);
    pinv(Wb8); pinv(Wb9); pinv(Wb10); pinv(Wb11); pinv(Wb12); pinv(Wb13); pinv(Wb14); pinv(Wb15);
    pinv(Wc0); pinv(Wc1); pinv(Wc2); pinv(Wc3); pinv(Wc4); pinv(Wc5); pinv(Wc6); pinv(Wc7);
    pinv(Wc8); pinv(Wc9); pinv(Wc10); pinv(Wc11); pinv(Wc12); pinv(Wc13); pinv(Wc14); pinv(Wc15);
    pinv(biasv);

    const float* xp  = xp0 + (size_t)b * Tn * 16 + jl;   // rows padded to 16, j>=10 are 0
    float*       h2w = h2seq + (size_t)b * Tn * Hn + jl;

    // prefetch ring, depth 16 (rows t=0..15)
    float x0 = xp[0*16],  x1 = xp[1*16],  x2 = xp[2*16],  x3 = xp[3*16];
    float x4 = xp[4*16],  x5 = xp[5*16],  x6 = xp[6*16],  x7 = xp[7*16];
    float x8 = xp[8*16],  x9 = xp[9*16],  x10 = xp[10*16], x11 = xp[11*16];
    float x12 = xp[12*16], x13 = xp[13*16], x14 = xp[14*16], x15 = xp[15*16];

    float vh1 = 0.f, vh2 = 0.f;            // h1/h2 state (lane jl holds index jl)
    float y0, y1, y2, y3, y4, y5, y6, y7;

    #define BLK_LO() do {                                   \
        STEP(x0, y0); x0 = xp[16*16];                       \
        STEP(x1, y1); x1 = xp[17*16];                       \
        STEP(x2, y2); x2 = xp[18*16];                       \
        STEP(x3, y3); x3 = xp[19*16];                       \
        STEP(x4, y4); x4 = xp[20*16];                       \
        STEP(x5, y5); x5 = xp[21*16];                       \
        STEP(x6, y6); x6 = xp[22*16];                       \
        STEP(x7, y7); x7 = xp[23*16];                       \
        if (okj) {                                          \
            h2w[0]  = y0; h2w[10] = y1; h2w[20] = y2; h2w[30] = y3; \
            h2w[40] = y4; h2w[50] = y5; h2w[60] = y6; h2w[70] = y7; \
        }                                                   \
        xp += 128; h2w += 80;                               \
    } while (0)
    #define BLK_HI() do {                                   \
        STEP(x8,  y0); x8  = xp[16*16];                     \
        STEP(x9,  y1); x9  = xp[17*16];                     \
        STEP(x10, y2); x10 = xp[18*16];                     \
        STEP(x11, y3); x11 = xp[19*16];                     \
        STEP(x12, y4); x12 = xp[20*16];                     \
        STEP(x13, y5); x13 = xp[21*16];                     \
        STEP(x14, y6); x14 = xp[22*16];                     \
        STEP(x15, y7); x15 = xp[23*16];                     \
        if (okj) {                                          \
            h2w[0]  = y0; h2w[10] = y1; h2w[20] = y2; h2w[30] = y3; \
            h2w[40] = y4; h2w[50] = y5; h2w[60] = y6; h2w[70] = y7; \
        }                                                   \
        xp += 128; h2w += 80;                               \
    } while (0)

    for (int p = 0; p < 64; ++p) {   // 64 x 16 = 1024 timesteps
        BLK_LO();
        BLK_HI();
    }
    #undef BLK_LO
    #undef BLK_HI

    if (okj) {
        hidden[b * Hn + jl]           = vh1;   // hidden[0] = h1[T-1]
        hidden[Bn * Hn + b * Hn + jl] = vh2;   // hidden[1] = h2[T-1]
    }
}

// =====================================================================
// K3: logits = h2seq * W_lin^T + b_lin, softmax over 128, f32 out.
// (unchanged — CONTROL)
// =====================================================================
__global__ __launch_bounds__(256) void k3_outproj(
    const float* __restrict__ h2seq,
    const float* __restrict__ Wlin,
    const float* __restrict__ blin,
    float* __restrict__ out)
{
    const int lane = threadIdx.x & 63;
    const int wid  = blockIdx.x * 4 + (threadIdx.x >> 6);  // grid=1024 -> 4096 waves
    const int g    = lane >> 4;
    const int i    = lane & 15;

    float wl[8][Hn], bl[8];
    #pragma unroll
    for (int s = 0; s < 8; ++s) {
        const int o = i * 8 + s;
        bl[s] = blin[o];
        #pragma unroll
        for (int k = 0; k < Hn; ++k) wl[s][k] = Wlin[o * Hn + k];
    }

    for (int r = wid * 4 + g; r < BTn; r += 4096 * 4) {
        const float hv = (i < Hn) ? h2seq[(size_t)r * Hn + i] : 0.f;
        float acc[8];
        #pragma unroll
        for (int s = 0; s < 8; ++s) acc[s] = bl[s];
        #pragma unroll
        for (int k = 0; k < Hn; ++k) {
            const float hk = __shfl(hv, k, 16);
            #pragma unroll
            for (int s = 0; s < 8; ++s) acc[s] = fmaf(wl[s][k], hk, acc[s]);
        }
        // softmax over this row's 128 logits (16 lanes x 8)
        float m = acc[0];
        #pragma unroll
        for (int s = 1; s < 8; ++s) m = fmaxf(m, acc[s]);
        #pragma unroll
        for (int off = 1; off < 16; off <<= 1) m = fmaxf(m, __shfl_xor(m, off, 16));
        float e[8], ssum = 0.f;
        #pragma unroll
        for (int s = 0; s < 8; ++s) { e[s] = __expf(acc[s] - m); ssum += e[s]; }
        #pragma unroll
        for (int off = 1; off < 16; off <<= 1) ssum += __shfl_xor(ssum, off, 16);
        const float inv = 1.0f / ssum;
        float4* op = reinterpret_cast<float4*>(out + (size_t)r * OUTn + i * 8);
        op[0] = make_float4(e[0] * inv, e[1] * inv, e[2] * inv, e[3] * inv);
        op[1] = make_float4(e[4] * inv, e[5] * inv, e[6] * inv, e[7] * inv);
    }
}

extern "C" void kernel_launch(void* const* d_in, const int* in_sizes, int n_in,
                              void* d_out, int out_size, void* d_ws, size_t ws_size,
                              hipStream_t stream)
{
    const float* x    = (const float*)d_in[0];
    const float* Wih0 = (const float*)d_in[1];
    const float* Whh0 = (const float*)d_in[2];
    const float* bih0 = (const float*)d_in[3];
    const float* bhh0 = (const float*)d_in[4];
    const float* Wih1 = (const float*)d_in[5];
    const float* Whh1 = (const float*)d_in[6];
    const float* bih1 = (const float*)d_in[7];
    const float* bhh1 = (const float*)d_in[8];
    const float* Wlin = (const float*)d_in[9];
    const float* blin = (const float*)d_in[10];

    float* out    = (float*)d_out;
    float* hidden = out + (size_t)BTn * OUTn;    // [2,B,H] tail of d_out

    float* xp0   = (float*)d_ws;                 // BTn*16 f32 = 16.8 MB
    float* h2seq = xp0 + (size_t)BTn * 16;       // BTn*10 f32 = 10.5 MB

    k1_inproj<<<BTn / 256, 256, 0, stream>>>(x, Wih0, bih0, bhh0, xp0);
    k2_recur<<<Bn / 4, 64, 0, stream>>>(xp0, Whh0, Wih1, Whh1, bih1, bhh1, h2seq, hidden);
    k3_outproj<<<1024, 256, 0, stream>>>(h2seq, Wlin, blin, out);
}